// Round 5
// baseline (362.062 us; speedup 1.0000x reference)
//
#include <hip/hip_runtime.h>
#include <math.h>

#define N_NODES 50000
#define N_EDGES 800000
#define DIN 256
#define DHID 128
#define DOUT 64
// Padded CSR row stride. In-degree ~ Poisson(16); P(deg > 64) ~ 1e-19 -> safe.
#define CSTRIDE 64
#define ZROW N_NODES            // sentinel row (kept zero)
#define NG4 12500               // 4-node groups
#define NPAD 50176              // padded count for zeroed counter arrays

#define DEGBLK 256
#define DCHUNK (N_EDGES / DEGBLK)    // 3125

// ---------------- k_setup block ranges: sentinel csr | degree atomics | weights ------
#define SB_SENT 3125
#define SB_DEG  (SB_SENT + DEGBLK)   // 3381
#define SB_TOT  (SB_DEG + 66)        // 3447

__global__ void k_setup(const int* __restrict__ src, const int* __restrict__ dst,
                        unsigned int* __restrict__ degS, unsigned int* __restrict__ degD,
                        unsigned int* __restrict__ csr32,
                        const float* __restrict__ W1, const float* __restrict__ b1,
                        const float* __restrict__ W3,
                        float* __restrict__ W13, float* __restrict__ bb,
                        float* __restrict__ Y0, float* __restrict__ Y1) {
    int bx = blockIdx.x, t = threadIdx.x;
    if (bx < SB_SENT) {
        // pre-fill every csr slot with the sentinel (k_mid's fill overwrites [0,deg))
        unsigned int v = (unsigned int)ZROW | ((unsigned int)ZROW << 16);
        uint2 o; o.x = v; o.y = v;
        ((uint2*)csr32)[bx * 256 + t] = o;
        return;
    }
    if (bx < SB_DEG) {
        // degrees via direct global atomics (counters zeroed by the preceding memset;
        // ~16 ops/address over 100K L2-resident addresses -> low contention)
        int base = (bx - SB_SENT) * DCHUNK;
        for (int i = t; i < DCHUNK; i += 256) {
            atomicAdd(&degS[src[base + i]], 1u);
            atomicAdd(&degD[dst[base + i]], 1u);
        }
        return;
    }
    int vb = bx - SB_DEG;                // 0..65
    if (vb == 65) {
        if (t < 64) Y0[(size_t)ZROW * 64 + t] = 0.f;          // zero sentinel row
        else if (t < 128) Y1[(size_t)ZROW * 64 + (t - 64)] = 0.f;
        return;
    }
    if (vb == 64) {
        if (t < DOUT) {
            float s = 0.f;
            for (int k = 0; k < DHID; ++k) s += b1[k] * W3[k * DOUT + t];
            bb[t] = s;
        }
        return;
    }
    int idx2 = vb * 256 + t;             // 16384 outputs of W13 = W1@W3
    int i = idx2 >> 6, j = idx2 & 63;
    float s = 0.f;
    for (int k = 0; k < DHID; ++k) s += W1[i * DHID + k] * W3[k * DOUT + j];
    W13[idx2] = s;
}

// ---------------- k_mid: gemm | norms+group-max | csr fill, fused as block ranges ----
// All three depend only on k_setup outputs and feed only the spmm passes.
#define MB_GEMM 782
#define MB_PREP 196
#define MB_FILL 256
#define MB_TOT (MB_GEMM + MB_PREP + MB_FILL)   // 1234

__global__ void k_mid(const float* __restrict__ X, const float* __restrict__ W13,
                      const unsigned int* __restrict__ degS,
                      const unsigned int* __restrict__ degD,
                      const int* __restrict__ src, const int* __restrict__ dst,
                      unsigned int* __restrict__ cnt, unsigned short* __restrict__ csr,
                      float* __restrict__ ns, float* __restrict__ nd,
                      float* __restrict__ cc, int* __restrict__ mG,
                      float* __restrict__ Y) {
    int bx = blockIdx.x, tid = threadIdx.x;
    if (bx < MB_GEMM) {
        // dense GEMM: Y[row] = ns[row] * (X @ W13), row-major [N+1][64]
        __shared__ float As[16][68];
        __shared__ float Bs[16][64];
        int tx = tid & 15, ty = tid >> 4;
        int row0 = bx * 64;
        float acc[4][4];
#pragma unroll
        for (int i = 0; i < 4; ++i)
#pragma unroll
            for (int j = 0; j < 4; ++j) acc[i][j] = 0.f;
        int lr = tid >> 2;
        int lk = (tid & 3) << 2;
        int arow = row0 + lr;
        if (arow > N_NODES - 1) arow = N_NODES - 1;   // clamp: garbage rows never stored
        for (int k0 = 0; k0 < DIN; k0 += 16) {
            float4 a = *(const float4*)(X + (size_t)arow * DIN + k0 + lk);
            As[lk + 0][lr] = a.x; As[lk + 1][lr] = a.y;
            As[lk + 2][lr] = a.z; As[lk + 3][lr] = a.w;
            float4 b = *(const float4*)(W13 + (size_t)(k0 + (tid >> 4)) * DOUT + ((tid & 15) << 2));
            *(float4*)&Bs[tid >> 4][(tid & 15) << 2] = b;
            __syncthreads();
#pragma unroll
            for (int k = 0; k < 16; ++k) {
                float4 av = *(const float4*)&As[k][ty << 2];
                float4 bv = *(const float4*)&Bs[k][tx << 2];
                float ar[4] = {av.x, av.y, av.z, av.w};
                float br[4] = {bv.x, bv.y, bv.z, bv.w};
#pragma unroll
                for (int i = 0; i < 4; ++i)
#pragma unroll
                    for (int j = 0; j < 4; ++j) acc[i][j] += ar[i] * br[j];
            }
            __syncthreads();
        }
        int qq = tx >> 2;
        int co = (tx & 3) << 2;
#pragma unroll
        for (int i = 0; i < 4; ++i) {
            int row = row0 + (ty << 2) + i;
            if (row < N_NODES) {
                unsigned int dsv = degS[row];
                float nsr = rsqrtf((float)(dsv ? dsv : 1u));
                float4 o;
                o.x = acc[i][0] * nsr; o.y = acc[i][1] * nsr;
                o.z = acc[i][2] * nsr; o.w = acc[i][3] * nsr;
                *(float4*)(Y + (size_t)row * 64 + (qq << 4) + co) = o;
            }
        }
    } else if (bx < MB_GEMM + MB_PREP) {
        // norms + per-4-node-group padded max degree
        if (tid < 64) {
            int wid = (bx - MB_GEMM) * 64 + tid;
            if (wid < NG4) {
                uint4 s4 = *(const uint4*)(degS + (wid << 2));
                uint4 d4 = *(const uint4*)(degD + (wid << 2));
                unsigned int dsv[4] = {s4.x, s4.y, s4.z, s4.w};
                unsigned int ddv[4] = {d4.x, d4.y, d4.z, d4.w};
                float fns[4], fnd[4], fcc[4];
                unsigned int mx = 0;
#pragma unroll
                for (int q = 0; q < 4; ++q) {
                    if (ddv[q] > mx) mx = ddv[q];
                    unsigned int a = dsv[q] ? dsv[q] : 1u;
                    unsigned int b = ddv[q] ? ddv[q] : 1u;
                    float fa = rsqrtf((float)a);
                    float fb = rsqrtf((float)b);
                    fns[q] = fa; fnd[q] = fb; fcc[q] = fa * fb;
                }
                float4 vns = {fns[0], fns[1], fns[2], fns[3]};
                float4 vnd = {fnd[0], fnd[1], fnd[2], fnd[3]};
                float4 vcc = {fcc[0], fcc[1], fcc[2], fcc[3]};
                *(float4*)(ns + (wid << 2)) = vns;
                *(float4*)(nd + (wid << 2)) = vnd;
                *(float4*)(cc + (wid << 2)) = vcc;
                int m = ((int)mx + 7) & ~7;
                mG[wid] = m > 64 ? 64 : m;
            }
        }
    } else {
        // csr fill: slot via global atomic return (cnt zeroed by memset)
        int base = (bx - MB_GEMM - MB_PREP) * DCHUNK;
        for (int i = tid; i < DCHUNK; i += 256) {
            int s = src[base + i], d = dst[base + i];
            unsigned int slot = atomicAdd(&cnt[d], 1u);
            if (slot < 64u) csr[((size_t)d << 6) + slot] = (unsigned short)s;
        }
    }
}

// ---------------- pull SpMM on row-major [N+1][64] (256 B rows) ---------------------
// Wave = 4 nodes x 16 col-lanes. csr rows staged once per wave (transposed in LDS,
// entry T of node n at rows[wid][4T+n]; 16 col-lanes broadcast-read the same u16).
// Loop bound m = pad8(max in-degree of the 4 nodes); slots [deg,m) hold the sentinel
// row ZROW (zero, L1-hot single line -> near-free). No shuffles: every lane owns a
// distinct (node, 4-col) quad and stores directly.
// MODE 0: y = cc*acc + ns*bb[col]; MODE 1: y = cc*acc; MODE 2: out = nd*acc + b3[col].

template <int MODE>
__launch_bounds__(256, 8)
__global__ void k_spmm(const float* __restrict__ xs, float* __restrict__ ys,
                       const unsigned short* __restrict__ csr,
                       const int* __restrict__ mG,
                       const float* __restrict__ cc, const float* __restrict__ ns,
                       const float* __restrict__ nd,
                       const float* __restrict__ bb, const float* __restrict__ b3) {
    __shared__ unsigned short rows[4][256];     // [wave][entry*4 + node] = 2 KB
    int wid = threadIdx.x >> 6, lane = threadIdx.x & 63;
    int g = blockIdx.x * 4 + wid;               // 0..12499 (grid exact)
    int node0 = g << 2;
    int n = lane >> 4, sl = lane & 15;
    // stage 4 csr rows (4 x 128 B): lane (n,sl) loads entries 4sl..4sl+3 of node n
    uint2 rv = *((const uint2*)(csr + ((size_t)(node0 + n) << 6)) + sl);
    unsigned short* bp = &rows[wid][(sl << 4) + n];
    bp[0]  = (unsigned short)(rv.x & 0xffffu);
    bp[4]  = (unsigned short)(rv.x >> 16);
    bp[8]  = (unsigned short)(rv.y & 0xffffu);
    bp[12] = (unsigned short)(rv.y >> 16);

    int m = __builtin_amdgcn_readfirstlane(mG[g]);

    int c16 = lane & 15;
    const unsigned short* rd = &rows[wid][n];   // entry T at rd[4T]
    const float* xq = xs + (c16 << 2);
    float ax = 0.f, ay = 0.f, az = 0.f, aw = 0.f;
#define LD(T) const float4 v##T = *(const float4*)(xq + ((size_t)rd[(T) << 2] << 6))
#define AC(T) ax += v##T.x; ay += v##T.y; az += v##T.z; aw += v##T.w
    if (m <= 8) {
        LD(0); LD(1); LD(2); LD(3); LD(4); LD(5); LD(6); LD(7);
        AC(0); AC(1); AC(2); AC(3); AC(4); AC(5); AC(6); AC(7);
    } else if (m <= 16) {
        LD(0); LD(1); LD(2); LD(3); LD(4); LD(5); LD(6); LD(7);
        AC(0); LD(8);  AC(1); LD(9);  AC(2); LD(10); AC(3); LD(11);
        AC(4); LD(12); AC(5); LD(13); AC(6); LD(14); AC(7); LD(15);
        AC(8); AC(9); AC(10); AC(11); AC(12); AC(13); AC(14); AC(15);
    } else if (m <= 24) {
        LD(0); LD(1); LD(2); LD(3); LD(4); LD(5); LD(6); LD(7);
        AC(0);  LD(8);  AC(1);  LD(9);  AC(2);  LD(10); AC(3);  LD(11);
        AC(4);  LD(12); AC(5);  LD(13); AC(6);  LD(14); AC(7);  LD(15);
        AC(8);  LD(16); AC(9);  LD(17); AC(10); LD(18); AC(11); LD(19);
        AC(12); LD(20); AC(13); LD(21); AC(14); LD(22); AC(15); LD(23);
        AC(16); AC(17); AC(18); AC(19); AC(20); AC(21); AC(22); AC(23);
    } else if (m <= 32) {
        LD(0); LD(1); LD(2); LD(3); LD(4); LD(5); LD(6); LD(7);
        AC(0);  LD(8);  AC(1);  LD(9);  AC(2);  LD(10); AC(3);  LD(11);
        AC(4);  LD(12); AC(5);  LD(13); AC(6);  LD(14); AC(7);  LD(15);
        AC(8);  LD(16); AC(9);  LD(17); AC(10); LD(18); AC(11); LD(19);
        AC(12); LD(20); AC(13); LD(21); AC(14); LD(22); AC(15); LD(23);
        AC(16); LD(24); AC(17); LD(25); AC(18); LD(26); AC(19); LD(27);
        AC(20); LD(28); AC(21); LD(29); AC(22); LD(30); AC(23); LD(31);
        AC(24); AC(25); AC(26); AC(27); AC(28); AC(29); AC(30); AC(31);
    } else {
        // m in (32,64]: ~0.06% of groups
        for (int T = 0; T < m; T += 8) {
            int o = T << 2;
            const float4 w0 = *(const float4*)(xq + ((size_t)rd[o]      << 6));
            const float4 w1 = *(const float4*)(xq + ((size_t)rd[o + 4]  << 6));
            const float4 w2 = *(const float4*)(xq + ((size_t)rd[o + 8]  << 6));
            const float4 w3 = *(const float4*)(xq + ((size_t)rd[o + 12] << 6));
            const float4 w4 = *(const float4*)(xq + ((size_t)rd[o + 16] << 6));
            const float4 w5 = *(const float4*)(xq + ((size_t)rd[o + 20] << 6));
            const float4 w6 = *(const float4*)(xq + ((size_t)rd[o + 24] << 6));
            const float4 w7 = *(const float4*)(xq + ((size_t)rd[o + 28] << 6));
            ax += w0.x; ay += w0.y; az += w0.z; aw += w0.w;
            ax += w1.x; ay += w1.y; az += w1.z; aw += w1.w;
            ax += w2.x; ay += w2.y; az += w2.z; aw += w2.w;
            ax += w3.x; ay += w3.y; az += w3.z; aw += w3.w;
            ax += w4.x; ay += w4.y; az += w4.z; aw += w4.w;
            ax += w5.x; ay += w5.y; az += w5.z; aw += w5.w;
            ax += w6.x; ay += w6.y; az += w6.z; aw += w6.w;
            ax += w7.x; ay += w7.y; az += w7.z; aw += w7.w;
        }
    }
#undef LD
#undef AC
    int node = node0 + n;
    int col = c16 << 2;
    float4 r;
    if (MODE == 0) {
        float cv = cc[node], nv = ns[node];
        float4 bv = *(const float4*)(bb + col);
        r.x = cv * ax + nv * bv.x; r.y = cv * ay + nv * bv.y;
        r.z = cv * az + nv * bv.z; r.w = cv * aw + nv * bv.w;
    } else if (MODE == 1) {
        float cv = cc[node];
        r.x = cv * ax; r.y = cv * ay; r.z = cv * az; r.w = cv * aw;
    } else {
        float dv = nd[node];
        float4 bv = *(const float4*)(b3 + col);
        r.x = dv * ax + bv.x; r.y = dv * ay + bv.y;
        r.z = dv * az + bv.z; r.w = dv * aw + bv.w;
    }
    *(float4*)(ys + ((size_t)node << 6) + col) = r;
}

// ---------------- launcher ----------------

extern "C" void kernel_launch(void* const* d_in, const int* in_sizes, int n_in,
                              void* d_out, int out_size, void* d_ws, size_t ws_size,
                              hipStream_t stream) {
    const float* X   = (const float*)d_in[0];
    const int*   src = (const int*)d_in[1];
    const int*   dst = (const int*)d_in[2];
    const float* W1  = (const float*)d_in[3];
    const float* b1  = (const float*)d_in[4];
    const float* W3  = (const float*)d_in[5];
    const float* b3  = (const float*)d_in[6];
    float* out = (float*)d_out;

    char* ws = (char*)d_ws;
    size_t off = 0;
    auto alloc = [&](size_t bytes) -> void* {
        void* p = ws + off;
        off = (off + bytes + 255) & ~(size_t)255;
        return p;
    };
    unsigned int*   zreg = (unsigned int*)alloc((size_t)3 * NPAD * 4);  // degS|degD|cnt
    unsigned int*   degS = zreg;
    unsigned int*   degD = zreg + NPAD;
    unsigned int*   cnt  = zreg + 2 * NPAD;
    float*          Y0   = (float*)alloc((size_t)(N_NODES + 1) * 64 * 4);
    float*          Y1   = (float*)alloc((size_t)(N_NODES + 1) * 64 * 4);
    unsigned short* csr  = (unsigned short*)alloc((size_t)N_NODES * CSTRIDE * 2);
    float*          ns   = (float*)alloc((size_t)N_NODES * 4);
    float*          nd   = (float*)alloc((size_t)N_NODES * 4);
    float*          cc   = (float*)alloc((size_t)N_NODES * 4);
    int*            mG   = (int*)alloc((size_t)NG4 * 4);
    float*          W13  = (float*)alloc((size_t)DIN * DOUT * 4);
    float*          bb   = (float*)alloc(DOUT * 4);

    hipMemsetAsync(zreg, 0, (size_t)3 * NPAD * 4, stream);

    k_setup<<<SB_TOT, 256, 0, stream>>>(src, dst, degS, degD, (unsigned int*)csr,
                                        W1, b1, W3, W13, bb, Y0, Y1);

    k_mid<<<MB_TOT, 256, 0, stream>>>(X, W13, degS, degD, src, dst, cnt, csr,
                                      ns, nd, cc, mG, Y0);

    // 6 propagation passes; bias bb injected in pass 1, b3 in pass 6
    k_spmm<0><<<3125, 256, 0, stream>>>(Y0, Y1, csr, mG, cc, ns, nd, bb, b3);
    k_spmm<1><<<3125, 256, 0, stream>>>(Y1, Y0, csr, mG, cc, ns, nd, bb, b3);
    k_spmm<1><<<3125, 256, 0, stream>>>(Y0, Y1, csr, mG, cc, ns, nd, bb, b3);
    k_spmm<1><<<3125, 256, 0, stream>>>(Y1, Y0, csr, mG, cc, ns, nd, bb, b3);
    k_spmm<1><<<3125, 256, 0, stream>>>(Y0, Y1, csr, mG, cc, ns, nd, bb, b3);
    k_spmm<2><<<3125, 256, 0, stream>>>(Y1, out, csr, mG, cc, ns, nd, bb, b3);
}

// Round 6
// 290.446 us; speedup vs baseline: 1.2466x; 1.2466x over previous
//
#include <hip/hip_runtime.h>
#include <math.h>

#define N_NODES 50000
#define N_EDGES 800000
#define DIN 256
#define DHID 128
#define DOUT 64
// Padded CSR row stride. In-degree ~ Poisson(16); P(deg > 64) ~ 1e-19 -> safe.
#define CSTRIDE 64
#define ZROW N_NODES            // sentinel row (kept zero)
#define HBLOCKS 128
#define HCHUNK (N_EDGES / HBLOCKS)     // 6250
#define HWORDS (N_NODES / 4)           // 12500
#define SLICE ((size_t)(N_NODES + 1) * 16)
#define NGROUPS (N_NODES / 4)          // 12500
#define P2BLOCKS 196                   // hpre blocks (12500/64 word-cols)

// ---------------- fat setup kernel: sentinel-fill csr, 2 histograms, weight folds ----
#define SB_SENT 3125
#define SB_HS (SB_SENT + HBLOCKS)       // 3253
#define SB_HD (SB_HS + HBLOCKS)         // 3381
#define SB_TOT (SB_HD + 66)             // 3447

__global__ void k_setup(const int* __restrict__ src, const int* __restrict__ dst,
                        unsigned int* __restrict__ pS, unsigned int* __restrict__ pD,
                        unsigned int* __restrict__ csr32,
                        const float* __restrict__ W1, const float* __restrict__ b1,
                        const float* __restrict__ W3,
                        float* __restrict__ W13, float* __restrict__ bb,
                        float* __restrict__ Y0, float* __restrict__ Y1) {
    __shared__ unsigned int h[HWORDS];
    int bx = blockIdx.x, t = threadIdx.x;
    if (bx < SB_SENT) {
        // pre-fill every csr slot with the sentinel (k_mid's fill overwrites [0,deg))
        unsigned int v = (unsigned int)ZROW | ((unsigned int)ZROW << 16);
        uint2 o; o.x = v; o.y = v;
        ((uint2*)csr32)[bx * 256 + t] = o;
        return;
    }
    if (bx < SB_HD) {
        // byte-packed LDS-privatized histogram (4 bins per u32); per-block
        // per-node counts <= total degree (<=64) << 255 -> no byte carry.
        const int* idx = (bx < SB_HS) ? src : dst;
        unsigned int* outp = (bx < SB_HS) ? pS : pD;
        int hb = bx - ((bx < SB_HS) ? SB_SENT : SB_HS);
        for (int w = t; w < HWORDS; w += 256) h[w] = 0u;
        __syncthreads();
        int base = hb * HCHUNK;
        for (int i = t; i < HCHUNK; i += 256) {
            int s = idx[base + i];
            atomicAdd(&h[s >> 2], 1u << ((s & 3) << 3));
        }
        __syncthreads();
        outp += (size_t)hb * HWORDS;
        for (int w = t; w < HWORDS; w += 256) outp[w] = h[w];
        return;
    }
    int vb = bx - SB_HD;                 // 0..65
    if (vb == 65) {
        if (t < 64) {                    // zero the sentinel row in Y0 (all 4 slices)
            int qq = t >> 4, c2 = t & 15;
            Y0[(size_t)qq * SLICE + ((size_t)ZROW << 4) + c2] = 0.f;
        } else if (t < 128) {            // and in Y1
            int t2 = t - 64;
            int qq = t2 >> 4, c2 = t2 & 15;
            Y1[(size_t)qq * SLICE + ((size_t)ZROW << 4) + c2] = 0.f;
        }
        return;
    }
    if (vb == 64) {
        if (t < DOUT) {
            float s = 0.f;
            for (int k = 0; k < DHID; ++k) s += b1[k] * W3[k * DOUT + t];
            bb[t] = s;
        }
        return;
    }
    int idx2 = vb * 256 + t;             // 16384 outputs of W13 = W1@W3
    int i = idx2 >> 6, j = idx2 & 63;
    float s = 0.f;
    for (int k = 0; k < DHID; ++k) s += W1[i * DHID + k] * W3[k * DOUT + j];
    W13[idx2] = s;
}

// ---------------- hpre: partial-sum + prefix + norms + group max-degree -------------
// thread = (col, sub): col = t>>2 owns packed word wid, sub = t&3 scans 32 of
// the 128 hist blocks. Packed byte sums never carry (per-node totals <= 64).
// No sort: ns/nd/cc written in ORIGINAL numbering; mG[wid] = pad8(max in-degree
// of the 4 nodes in word wid), clamped to 64 (the spmm loop bound).
__global__ void k_hpre(const unsigned int* __restrict__ pS,
                       const unsigned int* __restrict__ pD,
                       unsigned int* __restrict__ prefix,
                       float* __restrict__ ns, float* __restrict__ nd,
                       float* __restrict__ cc, int* __restrict__ mG) {
    __shared__ unsigned int sdw[64][4];
    __shared__ unsigned int sow[64][4];
    int t = threadIdx.x;
    int col = t >> 2, sub = t & 3;
    int wid = blockIdx.x * 64 + col;
    bool act = wid < HWORDS;
    unsigned int ps = 0, pd = 0;
    if (act) {
        int b0 = sub << 5;
#pragma unroll 4
        for (int b = b0; b < b0 + 32; ++b) {
            ps += pS[(size_t)b * HWORDS + wid];
            pd += pD[(size_t)b * HWORDS + wid];
        }
    }
    sdw[col][sub] = pd;
    sow[col][sub] = ps;
    __syncthreads();
    if (act) {
        unsigned int base = 0;
        for (int k = 0; k < sub; ++k) base += sdw[col][k];
        int b0 = sub << 5;
        unsigned int run = base;
        for (int b = b0; b < b0 + 32; ++b) {
            unsigned int w = pD[(size_t)b * HWORDS + wid];
            prefix[(size_t)b * HWORDS + wid] = run;
            run += w;
        }
        if (sub == 0) {
            unsigned int totd = sdw[col][0] + sdw[col][1] + sdw[col][2] + sdw[col][3];
            unsigned int toto = sow[col][0] + sow[col][1] + sow[col][2] + sow[col][3];
            unsigned int di[4] = {totd & 0xffu, (totd >> 8) & 0xffu,
                                  (totd >> 16) & 0xffu, totd >> 24};
            unsigned int dov[4] = {toto & 0xffu, (toto >> 8) & 0xffu,
                                   (toto >> 16) & 0xffu, toto >> 24};
            float4 vns, vnd, vcc;
            float* pns = &vns.x; float* pnd = &vnd.x; float* pcc = &vcc.x;
            unsigned int mx = 0;
#pragma unroll
            for (int q = 0; q < 4; ++q) {
                if (di[q] > mx) mx = di[q];
                unsigned int a = dov[q] < 1u ? 1u : dov[q];
                unsigned int b = di[q] < 1u ? 1u : di[q];
                float fa = 1.0f / sqrtf((float)a);
                float fb = 1.0f / sqrtf((float)b);
                pns[q] = fa; pnd[q] = fb; pcc[q] = fa * fb;
            }
            *(float4*)(ns + (wid << 2)) = vns;
            *(float4*)(nd + (wid << 2)) = vnd;
            *(float4*)(cc + (wid << 2)) = vcc;
            int m = ((int)mx + 7) & ~7;
            mG[wid] = m > 64 ? 64 : m;
        }
    }
}

// ---------------- k_mid: csr fill | dense GEMM, fused as block ranges ---------------
#define MB_FILL 128
#define MB_GEMM 782
#define MB_TOT (MB_FILL + MB_GEMM)     // 910

__global__ void k_mid(const int* __restrict__ src, const int* __restrict__ dst,
                      const unsigned int* __restrict__ prefix,
                      unsigned short* __restrict__ csr,
                      const float* __restrict__ X, const float* __restrict__ W13,
                      const float* __restrict__ ns, float* __restrict__ Y) {
    int bx = blockIdx.x, tid = threadIdx.x;
    if (bx < MB_FILL) {
        // csr fill (original numbering) using LDS running offsets only
        __shared__ unsigned int h[HWORDS];
        const unsigned int* prow = prefix + (size_t)bx * HWORDS;
        for (int w = tid; w < HWORDS; w += 256) h[w] = prow[w];
        __syncthreads();
        int base = bx * HCHUNK;
        for (int i = tid; i < HCHUNK; i += 256) {
            int s = src[base + i], d = dst[base + i];
            int sh = (d & 3) << 3;
            unsigned int old = atomicAdd(&h[d >> 2], 1u << sh);
            int slot = (int)((old >> sh) & 0xffu);
            csr[((size_t)d << 6) + slot] = (unsigned short)s;
        }
        return;
    }
    // dense GEMM: Y[row] = ns[row] * (X @ W13), 4-slice column layout
    __shared__ float As[16][68];
    __shared__ float Bs[16][64];
    int gb = bx - MB_FILL;
    int tx = tid & 15, ty = tid >> 4;
    int row0 = gb * 64;
    float acc[4][4];
#pragma unroll
    for (int i = 0; i < 4; ++i)
#pragma unroll
        for (int j = 0; j < 4; ++j) acc[i][j] = 0.f;
    int lr = tid >> 2;
    int lk = (tid & 3) << 2;
    int arow = row0 + lr;
    if (arow > N_NODES - 1) arow = N_NODES - 1;   // clamp: garbage rows never stored
    for (int k0 = 0; k0 < DIN; k0 += 16) {
        float4 a = *(const float4*)(X + (size_t)arow * DIN + k0 + lk);
        As[lk + 0][lr] = a.x; As[lk + 1][lr] = a.y;
        As[lk + 2][lr] = a.z; As[lk + 3][lr] = a.w;
        float4 b = *(const float4*)(W13 + (size_t)(k0 + (tid >> 4)) * DOUT + ((tid & 15) << 2));
        *(float4*)&Bs[tid >> 4][(tid & 15) << 2] = b;
        __syncthreads();
#pragma unroll
        for (int k = 0; k < 16; ++k) {
            float4 av = *(const float4*)&As[k][ty << 2];
            float4 bv = *(const float4*)&Bs[k][tx << 2];
            float ar[4] = {av.x, av.y, av.z, av.w};
            float br[4] = {bv.x, bv.y, bv.z, bv.w};
#pragma unroll
            for (int i = 0; i < 4; ++i)
#pragma unroll
                for (int j = 0; j < 4; ++j) acc[i][j] += ar[i] * br[j];
        }
        __syncthreads();
    }
    int qq = tx >> 2;
    int co = (tx & 3) << 2;
#pragma unroll
    for (int i = 0; i < 4; ++i) {
        int row = row0 + (ty << 2) + i;
        if (row < N_NODES) {
            float nsr = ns[row];
            float4 o;
            o.x = acc[i][0] * nsr; o.y = acc[i][1] * nsr;
            o.z = acc[i][2] * nsr; o.w = acc[i][3] * nsr;
            *(float4*)(Y + (size_t)qq * SLICE + ((size_t)row << 4) + co) = o;
        }
    }
}

// ---------------- sliced pull SpMM: 4 nodes x 4 edge-slots x float4 ------------------
// Round-0-proven structure; loop bound m = mG[g] (pad8 group max in-degree);
// slots [deg, m) hold the sentinel row (zero, L1-hot single line -> near-free).
// LDS rows stored TRANSPOSED [entry*4 + node]: hot-loop ds_read_u16 addresses
// hit 8 distinct banks -> conflict-free. q = (bx&7)>>1 pins each column slice
// to one XCD pair (3.2 MB slice << 8 MB L2 pair) for cross-pass L2 residency.
// MODE 0: y = cc*acc + ns*bb[col]; MODE 1: y = cc*acc;
// MODE 2: out[node] = nd*acc + b3[col]  (row-major [N][64]).

template <int MODE>
__launch_bounds__(256, 8)
__global__ void k_spmm(const float* __restrict__ xs, float* __restrict__ ys,
                       const unsigned short* __restrict__ csr,
                       const int* __restrict__ mG,
                       const float* __restrict__ cc, const float* __restrict__ ns,
                       const float* __restrict__ nd,
                       const float* __restrict__ bb, const float* __restrict__ b3) {
    __shared__ unsigned short rows[4][256];     // [wave][entry*4 + node] = 2 KB
    int wid  = threadIdx.x >> 6;
    int lane = threadIdx.x & 63;
    int q    = (blockIdx.x & 7) >> 1;
    int half = blockIdx.x & 1;
    int g    = (blockIdx.x >> 3) * 8 + wid * 2 + half;   // 4-node group id
    if (g >= NGROUPS) return;
    int node0 = g << 2;

    // stage 4 csr rows (4 x 128 B) into LDS, transposed: lane (nn,sl) loads
    // entries 4sl..4sl+3 of node nn and writes them at [(4sl+k)*4 + nn].
    int nn = lane >> 4, sl = lane & 15;
    const uint2* crow = (const uint2*)(csr + ((size_t)(node0 + nn) << 6)) + sl;
    uint2 rv = *crow;
    unsigned short* bp = &rows[wid][(sl << 4) + nn];
    bp[0]  = (unsigned short)(rv.x & 0xffffu);
    bp[4]  = (unsigned short)(rv.x >> 16);
    bp[8]  = (unsigned short)(rv.y & 0xffffu);
    bp[12] = (unsigned short)(rv.y >> 16);

    int m = __builtin_amdgcn_readfirstlane(mG[g]);       // pad8 group max, <= 64

    int n = lane >> 4, e = (lane >> 2) & 3, c4 = lane & 3;
    const unsigned short* rd = &rows[wid][(e << 2) + n];   // entry (e+4T) at rd[16T]
    const float* xq = xs + (size_t)q * SLICE + (c4 << 2);

    float ax = 0.f, ay = 0.f, az = 0.f, aw = 0.f;
#define LDV(T) const float4 v##T = *(const float4*)(xq + ((size_t)rd[16 * (T)] << 4))
#define ACCV(T) ax += v##T.x; ay += v##T.y; az += v##T.z; aw += v##T.w
    if (m <= 8) {
        LDV(0); LDV(1);
        ACCV(0); ACCV(1);
    } else if (m <= 16) {
        LDV(0); LDV(1); LDV(2); LDV(3);
        ACCV(0); ACCV(1); ACCV(2); ACCV(3);
    } else if (m <= 24) {
        LDV(0); LDV(1); LDV(2); LDV(3); LDV(4); LDV(5);
        ACCV(0); ACCV(1); ACCV(2); ACCV(3); ACCV(4); ACCV(5);
    } else if (m <= 32) {
        LDV(0); LDV(1); LDV(2); LDV(3); LDV(4); LDV(5); LDV(6); LDV(7);
        ACCV(0); ACCV(1); ACCV(2); ACCV(3); ACCV(4); ACCV(5); ACCV(6); ACCV(7);
    } else {
        for (int j2 = 0; j2 < m; j2 += 8) {
            int o = j2 << 2;
            const float4 a = *(const float4*)(xq + ((size_t)rd[o] << 4));
            const float4 b = *(const float4*)(xq + ((size_t)rd[o + 16] << 4));
            ax += a.x; ay += a.y; az += a.z; aw += a.w;
            ax += b.x; ay += b.y; az += b.z; aw += b.w;
        }
    }
#undef LDV
#undef ACCV
    // reduce over edge-slots e (lane bits 2..3)
    ax += __shfl_xor(ax, 4);  ay += __shfl_xor(ay, 4);
    az += __shfl_xor(az, 4);  aw += __shfl_xor(aw, 4);
    ax += __shfl_xor(ax, 8);  ay += __shfl_xor(ay, 8);
    az += __shfl_xor(az, 8);  aw += __shfl_xor(aw, 8);

    int nodeL = node0 + n;
    int colq  = (q << 4) + (c4 << 2);
    float4 r;
    if (MODE == 0) {
        float cv = cc[nodeL], nv = ns[nodeL];
        float4 bv = *(const float4*)(bb + colq);
        r.x = cv * ax + nv * bv.x; r.y = cv * ay + nv * bv.y;
        r.z = cv * az + nv * bv.z; r.w = cv * aw + nv * bv.w;
    } else if (MODE == 1) {
        float cv = cc[nodeL];
        r.x = cv * ax; r.y = cv * ay; r.z = cv * az; r.w = cv * aw;
    } else {
        float dv = nd[nodeL];
        float4 bv = *(const float4*)(b3 + colq);
        r.x = dv * ax + bv.x; r.y = dv * ay + bv.y;
        r.z = dv * az + bv.z; r.w = dv * aw + bv.w;
    }
    if (e == 0) {
        if (MODE == 2) {
            *(float4*)(ys + ((size_t)nodeL << 6) + colq) = r;
        } else {
            *(float4*)(ys + (size_t)q * SLICE + ((size_t)nodeL << 4) + (c4 << 2)) = r;
        }
    }
}

// ---------------- launcher ----------------

extern "C" void kernel_launch(void* const* d_in, const int* in_sizes, int n_in,
                              void* d_out, int out_size, void* d_ws, size_t ws_size,
                              hipStream_t stream) {
    const float* X   = (const float*)d_in[0];
    const int*   src = (const int*)d_in[1];
    const int*   dst = (const int*)d_in[2];
    const float* W1  = (const float*)d_in[3];
    const float* b1  = (const float*)d_in[4];
    const float* W3  = (const float*)d_in[5];
    const float* b3  = (const float*)d_in[6];
    float* out = (float*)d_out;

    char* ws = (char*)d_ws;
    size_t off = 0;
    auto alloc = [&](size_t bytes) -> void* {
        void* p = ws + off;
        off = (off + bytes + 255) & ~(size_t)255;
        return p;
    };
    unsigned int*   pS   = (unsigned int*)alloc((size_t)HBLOCKS * HWORDS * 4);
    unsigned int*   pD   = (unsigned int*)alloc((size_t)HBLOCKS * HWORDS * 4);
    unsigned int*   pref = (unsigned int*)alloc((size_t)HBLOCKS * HWORDS * 4);
    float*          Y0   = (float*)alloc(SLICE * 4 * 4);
    float*          Y1   = (float*)alloc(SLICE * 4 * 4);
    unsigned short* csr  = (unsigned short*)alloc((size_t)N_NODES * CSTRIDE * 2);
    float*          ns   = (float*)alloc((size_t)N_NODES * 4);
    float*          nd   = (float*)alloc((size_t)N_NODES * 4);
    float*          cc   = (float*)alloc((size_t)N_NODES * 4);
    int*            mG   = (int*)alloc((size_t)NGROUPS * 4);
    float*          W13  = (float*)alloc((size_t)DIN * DOUT * 4);
    float*          bb   = (float*)alloc(DOUT * 4);

    const int sblk = 1563 * 8;   // 12504 blocks -> 12500 groups x 4 slices

    k_setup<<<SB_TOT, 256, 0, stream>>>(src, dst, pS, pD, (unsigned int*)csr,
                                        W1, b1, W3, W13, bb, Y0, Y1);
    k_hpre<<<P2BLOCKS, 256, 0, stream>>>(pS, pD, pref, ns, nd, cc, mG);
    k_mid<<<MB_TOT, 256, 0, stream>>>(src, dst, pref, csr, X, W13, ns, Y0);

    // 6 propagation passes; bias bb injected in pass 1, b3 in pass 6
    k_spmm<0><<<sblk, 256, 0, stream>>>(Y0, Y1, csr, mG, cc, ns, nd, bb, b3);
    k_spmm<1><<<sblk, 256, 0, stream>>>(Y1, Y0, csr, mG, cc, ns, nd, bb, b3);
    k_spmm<1><<<sblk, 256, 0, stream>>>(Y0, Y1, csr, mG, cc, ns, nd, bb, b3);
    k_spmm<1><<<sblk, 256, 0, stream>>>(Y1, Y0, csr, mG, cc, ns, nd, bb, b3);
    k_spmm<1><<<sblk, 256, 0, stream>>>(Y0, Y1, csr, mG, cc, ns, nd, bb, b3);
    k_spmm<2><<<sblk, 256, 0, stream>>>(Y1, out, csr, mG, cc, ns, nd, bb, b3);
}